// Round 4
// baseline (565.597 us; speedup 1.0000x reference)
//
#include <hip/hip_runtime.h>
#include <stdint.h>
#include <math.h>

#define B_ 4
#define S_ 2048
#define C_ 256
#define H_ 8

typedef short bf16x8 __attribute__((ext_vector_type(8)));
typedef float f32x4 __attribute__((ext_vector_type(4)));
typedef float f32x16 __attribute__((ext_vector_type(16)));

static __device__ __forceinline__ short f2bf(float f) {
  uint32_t u = __float_as_uint(f);
  u = (u + 0x7fffu + ((u >> 16) & 1u)) >> 16;
  return (short)u;
}

static __device__ __forceinline__ int cvtpk(float lo, float hi) {
  int r;
  asm("v_cvt_pk_bf16_f32 %0, %1, %2" : "=v"(r) : "v"(lo), "v"(hi));
  return r;
}

static __device__ __forceinline__ bf16x8 pack4(int a, int b, int c, int d) {
  union { int i[4]; bf16x8 v; } u;
  u.i[0] = a; u.i[1] = b; u.i[2] = c; u.i[3] = d;
  return u.v;
}

static __device__ __forceinline__ void gld16(const void* g, void* l) {
  __builtin_amdgcn_global_load_lds(
      (const __attribute__((address_space(1))) uint32_t*)g,
      (__attribute__((address_space(3))) uint32_t*)l, 16, 0, 0);
}

// ---------------- elementwise convert fp32 -> bf16 ----------------
__global__ void cvt_f32_bf16(const float* __restrict__ in, short* __restrict__ out, int n) {
  int i = (blockIdx.x * 256 + threadIdx.x) * 8;
  if (i >= n) return;
  float4 a = *(const float4*)(in + i);
  float4 b = *(const float4*)(in + i + 4);
  bf16x8 r;
  r[0] = f2bf(a.x); r[1] = f2bf(a.y); r[2] = f2bf(a.z); r[3] = f2bf(a.w);
  r[4] = f2bf(b.x); r[5] = f2bf(b.y); r[6] = f2bf(b.z); r[7] = f2bf(b.w);
  *(bf16x8*)(out + i) = r;
}

// ---------------- transpose-convert: in fp32 (R x Cc) -> out bf16 (Cc x R) ----
__global__ void transpose_cvt(const float* __restrict__ in, short* __restrict__ out,
                              int R, int Cc) {
  __shared__ float t[32][33];
  int cb = blockIdx.x * 32, rb = blockIdx.y * 32;
  int tr = threadIdx.x >> 5;   // 0..7
  int tc = threadIdx.x & 31;
#pragma unroll
  for (int i = 0; i < 4; i++)
    t[tr + i * 8][tc] = in[(size_t)(rb + tr + i * 8) * Cc + cb + tc];
  __syncthreads();
#pragma unroll
  for (int i = 0; i < 4; i++)
    out[(size_t)(cb + tr + i * 8) * R + rb + tc] = f2bf(t[tc][tr + i * 8]);
}

// ---------------- GEMM: A (MxK bf16) * Bt^T (Bt is NxK bf16) + bias ----------
template<int MODE>
__global__ void __launch_bounds__(256, 2) gemm_k(
    const short* __restrict__ A, const short* __restrict__ Bt,
    const float* __restrict__ bias, float scale, void* __restrict__ out,
    int M, int N, int K) {
  __shared__ char smem[36864];
  const int tid = threadIdx.x;
  const int l = tid & 63;
  const int w = tid >> 6;
  const int wr = w >> 1, wc = w & 1;
  const int mbase = blockIdx.y * 128;
  const int nbase = blockIdx.x * 128;

  const f32x4 fzero = {0.f, 0.f, 0.f, 0.f};
  f32x4 acc[4][4];
#pragma unroll
  for (int i = 0; i < 4; i++)
#pragma unroll
    for (int j = 0; j < 4; j++) acc[i][j] = fzero;

  const int nkt = K >> 5;
  for (int kt = 0; kt < nkt; ++kt) {
#pragma unroll
    for (int c = 0; c < 2; c++) {
      int row = c * 64 + w * 16 + (l >> 2);
      const short* ga = A + (size_t)(mbase + row) * K + kt * 32 + (l & 3) * 8;
      gld16(ga, smem + (c * 4 + w) * 1024);
      const short* gb = Bt + (size_t)(nbase + row) * K + kt * 32 + (l & 3) * 8;
      gld16(gb, smem + 8192 + (c * 4 + w) * 1024);
    }
    __syncthreads();
    bf16x8 af[4], bf[4];
#pragma unroll
    for (int mf = 0; mf < 4; mf++)
      af[mf] = *(const bf16x8*)(smem + (wr * 64 + mf * 16 + (l & 15)) * 64 + ((l >> 4) << 4));
#pragma unroll
    for (int nf = 0; nf < 4; nf++)
      bf[nf] = *(const bf16x8*)(smem + 8192 + (wc * 64 + nf * 16 + (l & 15)) * 64 + ((l >> 4) << 4));
#pragma unroll
    for (int mf = 0; mf < 4; mf++)
#pragma unroll
      for (int nf = 0; nf < 4; nf++)
        acc[mf][nf] = __builtin_amdgcn_mfma_f32_16x16x32_bf16(af[mf], bf[nf], acc[mf][nf], 0, 0, 0);
    __syncthreads();
  }

  if (MODE == 0) {
#pragma unroll
    for (int mf = 0; mf < 4; mf++)
#pragma unroll
      for (int nf = 0; nf < 4; nf++)
#pragma unroll
        for (int i = 0; i < 4; i++) {
          int m = mbase + wr * 64 + mf * 16 + (l >> 4) * 4 + i;
          int n = nbase + wc * 64 + nf * 16 + (l & 15);
          float v = (acc[mf][nf][i] + bias[n]) * scale;
          int b = m >> 11, s = m & 2047;
          int h = n >> 8, d = n & 255;
          ((short*)out)[((size_t)(b * H_ + h) * S_ + s) * C_ + d] = f2bf(v);
        }
  } else if (MODE == 2) {
#pragma unroll
    for (int mf = 0; mf < 4; mf++)
#pragma unroll
      for (int nf = 0; nf < 4; nf++)
#pragma unroll
        for (int i = 0; i < 4; i++) {
          int m = mbase + wr * 64 + mf * 16 + (l >> 4) * 4 + i;
          int n = nbase + wc * 64 + nf * 16 + (l & 15);
          ((float*)out)[(size_t)m * N + n] = acc[mf][nf][i] + bias[n];
        }
  } else {
    short* T = (short*)smem;  // [128][136]
#pragma unroll
    for (int mf = 0; mf < 4; mf++)
#pragma unroll
      for (int nf = 0; nf < 4; nf++)
#pragma unroll
        for (int i = 0; i < 4; i++) {
          int ml = wr * 64 + mf * 16 + (l >> 4) * 4 + i;
          int nl = wc * 64 + nf * 16 + (l & 15);
          float v = acc[mf][nf][i] + bias[nbase + nl];
          T[ml * 136 + nl] = f2bf(v);
        }
    __syncthreads();
    int b = mbase >> 11, s0 = mbase & 2047;
    int h = nbase >> 8, d0 = nbase & 255;
#pragma unroll
    for (int r = 0; r < 8; r++) {
      int dl = r * 16 + (tid >> 4);
      int sc = (tid & 15) * 8;
      bf16x8 pack;
#pragma unroll
      for (int j = 0; j < 8; j++) pack[j] = T[(sc + j) * 136 + dl];
      *(bf16x8*)((short*)out + ((size_t)(b * H_ + h) * C_ + d0 + dl) * S_ + s0 + sc) = pack;
    }
  }
}

// ---------------- flash attention (8 waves, double-buffered, counted vmcnt) --
// grid 256 = 1 block/CU. orig = head*8 + qtile, XCD-chunked (4 heads/XCD).
// Wave w owns 32 q-rows. LDS: 2 x { Ks[64 rows][512B] | Vs[64 rows][512B] }.
// Per-wave math identical to verified round-3 kernel (swapped QK^T, T12 pack).
__global__ void __launch_bounds__(512, 2) attn_k(
    const short* __restrict__ Qg, const short* __restrict__ Kg,
    const short* __restrict__ Vtg, short* __restrict__ Ag) {
  __shared__ char smem[131072];
  const int tid = threadIdx.x, l = tid & 63, w = tid >> 6;   // w = 0..7
  const int hi = l >> 5;
  const int lq = l & 31;

  const int orig = (blockIdx.x & 7) * 32 + (blockIdx.x >> 3);  // bijective XCD chunk
  const int head = orig >> 3;
  const int qbase = (orig & 7) * 256 + w * 32;

  // Q fragments (B-operand): lane col q = lq, elem j <-> d = ks*16 + hi*8 + j
  bf16x8 qf[16];
  {
    const short* qb = Qg + ((size_t)head * S_ + qbase + lq) * C_;
#pragma unroll
    for (int ks = 0; ks < 16; ks++)
      qf[ks] = *(const bf16x8*)(qb + ks * 16 + hi * 8);
  }

  f32x16 o[8];
#pragma unroll
  for (int dt = 0; dt < 8; dt++)
#pragma unroll
    for (int r = 0; r < 16; r++) o[dt][r] = 0.0f;
  float mrun = -__builtin_inff();
  float lrun = 0.0f;

  // staging bases: wave handles segments sg = j*8+w (j=0..3), rows rr = j*16+c0
  uint32_t bk[2], bv[2];
  {
    const int c0 = w * 2 + hi;  // 0..15
#pragma unroll
    for (int p = 0; p < 2; p++) {
      int row = p * 16 + c0;            // 0..31
      int cs = lq ^ row;
      bk[p] = (uint32_t)(row * 512 + cs * 16);
      bv[p] = (uint32_t)((row * 4 + (cs >> 3)) * 4096 + (cs & 7) * 16);
    }
  }

  const char* kp = (const char*)Kg + (size_t)head * S_ * C_ * 2;
  const char* vp = (const char*)Vtg + (size_t)head * C_ * S_ * 2;

  // STAGE tile kt into buffer buf (8 gld16 per wave: 4 K + 4 V)
  auto STAGE = [&](int kt, int buf) {
    char* Kd = smem + buf * 65536;
    char* Vd = Kd + 32768;
    const char* kq = kp + (size_t)kt * 32768;
    const char* vq = vp + (size_t)kt * 128;
#pragma unroll
    for (int j = 0; j < 4; j++)
      gld16(kq + (uint32_t)((j >> 1) * 16384) + bk[j & 1], Kd + (j * 8 + w) * 1024);
#pragma unroll
    for (int j = 0; j < 4; j++)
      gld16(vq + (uint32_t)((j >> 1) * 524288) + bv[j & 1], Vd + (j * 8 + w) * 1024);
  };

  STAGE(0, 0);

#pragma unroll 2
  for (int kt = 0; kt < 32; ++kt) {
    const int cur = kt & 1;
    if (kt < 31) {
      STAGE(kt + 1, cur ^ 1);
      asm volatile("s_waitcnt vmcnt(8)" ::: "memory");  // cur's 8 done, next in flight
    } else {
      asm volatile("s_waitcnt vmcnt(0)" ::: "memory");
    }
    __builtin_amdgcn_s_barrier();

    char* Ks = smem + cur * 65536;
    char* Vs = Ks + 32768;

#pragma unroll
    for (int n = 0; n < 2; n++) {
      // ---- S^T tile: 32 k-rows x 32 q
      f32x16 st;
#pragma unroll
      for (int r = 0; r < 16; r++) st[r] = 0.0f;
      __builtin_amdgcn_s_setprio(1);
#pragma unroll
      for (int ks = 0; ks < 16; ks++) {
        bf16x8 kf = *(const bf16x8*)(Ks + (n * 32 + lq) * 512 + (((ks * 2 + hi) ^ lq) << 4));
        st = __builtin_amdgcn_mfma_f32_32x32x16_bf16(kf, qf[ks], st, 0, 0, 0);
      }
      __builtin_amdgcn_s_setprio(0);

      // ---- online softmax (lane owns q = lq; regs = 16 of 32 k-rows)
      float pm = st[0];
#pragma unroll
      for (int r = 1; r < 16; r++) pm = fmaxf(pm, st[r]);
      pm = fmaxf(pm, __shfl_xor(pm, 32));
      if (!__all(pm <= mrun + 8.0f)) {     // defer-max (T13)
        float mn = fmaxf(mrun, pm);
        float al = exp2f((mrun - mn) * 1.44269504f);
        mrun = mn;
        lrun *= al;
#pragma unroll
        for (int dt = 0; dt < 8; dt++) o[dt] *= al;
      }
      float mL = mrun * 1.44269504f;
      float rs = 0.f;
#pragma unroll
      for (int r = 0; r < 16; r++) {
        float p = exp2f(st[r] * 1.44269504f - mL);
        st[r] = p;
        rs += p;
      }
      rs += __shfl_xor(rs, 32);
      lrun += rs;

      // ---- pack + PV in two halves (T12; halved live temps)
      __builtin_amdgcn_s_setprio(1);
      {
        int a0 = cvtpk(st[0], st[1]), a1 = cvtpk(st[2], st[3]);
        int a2 = cvtpk(st[4], st[5]), a3 = cvtpk(st[6], st[7]);
        auto s0 = __builtin_amdgcn_permlane32_swap(a0, a2, false, false);
        auto s1 = __builtin_amdgcn_permlane32_swap(a1, a3, false, false);
        bf16x8 pf0 = pack4(s0[0], s1[0], s0[1], s1[1]);  // k 0..15 of half-tile
#pragma unroll
        for (int dt = 0; dt < 8; dt++) {
          int rV = dt * 8 + (lq >> 2);
          int csb = ((lq & 3) << 3) + n * 4 + hi;
          bf16x8 v0 = *(const bf16x8*)(Vs + rV * 512 + ((csb ^ (rV & 31)) << 4));
          o[dt] = __builtin_amdgcn_mfma_f32_32x32x16_bf16(v0, pf0, o[dt], 0, 0, 0);
        }
      }
      {
        int a4 = cvtpk(st[8], st[9]),   a5 = cvtpk(st[10], st[11]);
        int a6 = cvtpk(st[12], st[13]), a7 = cvtpk(st[14], st[15]);
        auto s2 = __builtin_amdgcn_permlane32_swap(a4, a6, false, false);
        auto s3 = __builtin_amdgcn_permlane32_swap(a5, a7, false, false);
        bf16x8 pf1 = pack4(s2[0], s3[0], s2[1], s3[1]);  // k 16..31 of half-tile
#pragma unroll
        for (int dt = 0; dt < 8; dt++) {
          int rV = dt * 8 + (lq >> 2);
          int csb = ((lq & 3) << 3) + n * 4 + hi + 2;
          bf16x8 v1 = *(const bf16x8*)(Vs + rV * 512 + ((csb ^ (rV & 31)) << 4));
          o[dt] = __builtin_amdgcn_mfma_f32_32x32x16_bf16(v1, pf1, o[dt], 0, 0, 0);
        }
      }
      __builtin_amdgcn_s_setprio(0);
    }

    asm volatile("" ::: "memory");      // pin reads before barrier
    __builtin_amdgcn_s_barrier();       // cur free for restage at kt+1
  }

  // ---- epilogue: O^T (d regs x q cols) -> LDS (swizzled) -> coalesced store
  char* ob = smem + w * 16384;  // per-wave 32 q-rows x 512B
  float inv = 1.0f / lrun;
#pragma unroll
  for (int dt = 0; dt < 8; dt++) {
#pragma unroll
    for (int m = 0; m < 4; m++) {
      int lo32 = cvtpk(o[dt][4 * m + 0] * inv, o[dt][4 * m + 1] * inv);
      int hi32 = cvtpk(o[dt][4 * m + 2] * inv, o[dt][4 * m + 3] * inv);
      int cs = (dt * 4 + m) ^ lq;
      int* p = (int*)(ob + lq * 512 + cs * 16 + hi * 8);
      p[0] = lo32; p[1] = hi32;
    }
  }
  int bb = head >> 3, hh = head & 7;
#pragma unroll
  for (int pi = 0; pi < 16; pi++) {
    int qr = pi * 2 + hi;
    bf16x8 v = *(const bf16x8*)(ob + qr * 512 + ((lq ^ qr) << 4));
    size_t g = ((size_t)(bb * S_ + qbase + qr) * (H_ * C_)) + hh * C_ + lq * 8;
    *(bf16x8*)(Ag + g) = v;
  }
}

// ---------------- launch ----------------------------------------------------
extern "C" void kernel_launch(void* const* d_in, const int* in_sizes, int n_in,
                              void* d_out, int out_size, void* d_ws, size_t ws_size,
                              hipStream_t stream) {
  const float* x  = (const float*)d_in[0];
  const float* Wq = (const float*)d_in[1];
  const float* bq = (const float*)d_in[2];
  const float* Wk = (const float*)d_in[3];
  const float* bk = (const float*)d_in[4];
  const float* Wv = (const float*)d_in[5];
  const float* bv = (const float*)d_in[6];
  const float* Wo = (const float*)d_in[7];
  const float* bo = (const float*)d_in[8];

  char* ws = (char*)d_ws;
  short* xb  = (short*)(ws);               //  4 MB
  short* WqT = (short*)(ws + 4194304);     //  1 MB
  short* WkT = (short*)(ws + 5242880);
  short* WvT = (short*)(ws + 6291456);
  short* WoT = (short*)(ws + 7340032);
  short* Qg  = (short*)(ws + 8388608);     // 32 MB (B,H,S,C)
  short* Kg  = (short*)(ws + 41943040);    // 32 MB (B,H,S,C)
  short* Vt  = (short*)(ws + 75497472);    // 32 MB (B,H,C,S)
  short* Ag  = (short*)(ws + 109051904);   // 32 MB (B,S,H*C)

  cvt_f32_bf16<<<1024, 256, 0, stream>>>(x, xb, 8192 * 256);
  transpose_cvt<<<dim3(64, 8), 256, 0, stream>>>(Wq, WqT, 256, 2048);
  transpose_cvt<<<dim3(64, 8), 256, 0, stream>>>(Wk, WkT, 256, 2048);
  transpose_cvt<<<dim3(64, 8), 256, 0, stream>>>(Wv, WvT, 256, 2048);
  transpose_cvt<<<dim3(8, 64), 256, 0, stream>>>(Wo, WoT, 2048, 256);

  const float sc = 0.25f;  // 256^(-1/4)
  gemm_k<0><<<dim3(16, 64), 256, 0, stream>>>(xb, WqT, bq, sc, Qg, 8192, 2048, 256);
  gemm_k<0><<<dim3(16, 64), 256, 0, stream>>>(xb, WkT, bk, sc, Kg, 8192, 2048, 256);
  gemm_k<1><<<dim3(16, 64), 256, 0, stream>>>(xb, WvT, bv, 1.0f, Vt, 8192, 2048, 256);
  attn_k<<<256, 512, 0, stream>>>(Qg, Kg, Vt, Ag);
  gemm_k<2><<<dim3(2, 64), 256, 0, stream>>>(Ag, WoT, bo, 1.0f, (float*)d_out, 8192, 256, 2048);
}

// Round 5
// 396.345 us; speedup vs baseline: 1.4270x; 1.4270x over previous
//
#include <hip/hip_runtime.h>
#include <stdint.h>
#include <math.h>

#define B_ 4
#define S_ 2048
#define C_ 256
#define H_ 8

typedef short bf16x8 __attribute__((ext_vector_type(8)));
typedef float f32x4 __attribute__((ext_vector_type(4)));
typedef float f32x16 __attribute__((ext_vector_type(16)));

static __device__ __forceinline__ short f2bf(float f) {
  uint32_t u = __float_as_uint(f);
  u = (u + 0x7fffu + ((u >> 16) & 1u)) >> 16;
  return (short)u;
}

static __device__ __forceinline__ int cvtpk(float lo, float hi) {
  int r;
  asm("v_cvt_pk_bf16_f32 %0, %1, %2" : "=v"(r) : "v"(lo), "v"(hi));
  return r;
}

static __device__ __forceinline__ bf16x8 pack4(int a, int b, int c, int d) {
  union { int i[4]; bf16x8 v; } u;
  u.i[0] = a; u.i[1] = b; u.i[2] = c; u.i[3] = d;
  return u.v;
}

static __device__ __forceinline__ void gld16(const void* g, void* l) {
  __builtin_amdgcn_global_load_lds(
      (const __attribute__((address_space(1))) uint32_t*)g,
      (__attribute__((address_space(3))) uint32_t*)l, 16, 0, 0);
}

// ---------------- elementwise convert fp32 -> bf16 ----------------
__global__ void cvt_f32_bf16(const float* __restrict__ in, short* __restrict__ out, int n) {
  int i = (blockIdx.x * 256 + threadIdx.x) * 8;
  if (i >= n) return;
  float4 a = *(const float4*)(in + i);
  float4 b = *(const float4*)(in + i + 4);
  bf16x8 r;
  r[0] = f2bf(a.x); r[1] = f2bf(a.y); r[2] = f2bf(a.z); r[3] = f2bf(a.w);
  r[4] = f2bf(b.x); r[5] = f2bf(b.y); r[6] = f2bf(b.z); r[7] = f2bf(b.w);
  *(bf16x8*)(out + i) = r;
}

// ---------------- transpose-convert: in fp32 (R x Cc) -> out bf16 (Cc x R) ----
__global__ void transpose_cvt(const float* __restrict__ in, short* __restrict__ out,
                              int R, int Cc) {
  __shared__ float t[32][33];
  int cb = blockIdx.x * 32, rb = blockIdx.y * 32;
  int tr = threadIdx.x >> 5;   // 0..7
  int tc = threadIdx.x & 31;
#pragma unroll
  for (int i = 0; i < 4; i++)
    t[tr + i * 8][tc] = in[(size_t)(rb + tr + i * 8) * Cc + cb + tc];
  __syncthreads();
#pragma unroll
  for (int i = 0; i < 4; i++)
    out[(size_t)(cb + tr + i * 8) * R + rb + tc] = f2bf(t[tc][tr + i * 8]);
}

// ---------------- GEMM: A (MxK bf16) * Bt^T (Bt is NxK bf16) + bias ----------
template<int MODE>
__global__ void __launch_bounds__(256, 2) gemm_k(
    const short* __restrict__ A, const short* __restrict__ Bt,
    const float* __restrict__ bias, float scale, void* __restrict__ out,
    int M, int N, int K) {
  __shared__ char smem[36864];
  const int tid = threadIdx.x;
  const int l = tid & 63;
  const int w = tid >> 6;
  const int wr = w >> 1, wc = w & 1;
  const int mbase = blockIdx.y * 128;
  const int nbase = blockIdx.x * 128;

  const f32x4 fzero = {0.f, 0.f, 0.f, 0.f};
  f32x4 acc[4][4];
#pragma unroll
  for (int i = 0; i < 4; i++)
#pragma unroll
    for (int j = 0; j < 4; j++) acc[i][j] = fzero;

  const int nkt = K >> 5;
  for (int kt = 0; kt < nkt; ++kt) {
#pragma unroll
    for (int c = 0; c < 2; c++) {
      int row = c * 64 + w * 16 + (l >> 2);
      const short* ga = A + (size_t)(mbase + row) * K + kt * 32 + (l & 3) * 8;
      gld16(ga, smem + (c * 4 + w) * 1024);
      const short* gb = Bt + (size_t)(nbase + row) * K + kt * 32 + (l & 3) * 8;
      gld16(gb, smem + 8192 + (c * 4 + w) * 1024);
    }
    __syncthreads();
    bf16x8 af[4], bf[4];
#pragma unroll
    for (int mf = 0; mf < 4; mf++)
      af[mf] = *(const bf16x8*)(smem + (wr * 64 + mf * 16 + (l & 15)) * 64 + ((l >> 4) << 4));
#pragma unroll
    for (int nf = 0; nf < 4; nf++)
      bf[nf] = *(const bf16x8*)(smem + 8192 + (wc * 64 + nf * 16 + (l & 15)) * 64 + ((l >> 4) << 4));
#pragma unroll
    for (int mf = 0; mf < 4; mf++)
#pragma unroll
      for (int nf = 0; nf < 4; nf++)
        acc[mf][nf] = __builtin_amdgcn_mfma_f32_16x16x32_bf16(af[mf], bf[nf], acc[mf][nf], 0, 0, 0);
    __syncthreads();
  }

  if (MODE == 0) {
#pragma unroll
    for (int mf = 0; mf < 4; mf++)
#pragma unroll
      for (int nf = 0; nf < 4; nf++)
#pragma unroll
        for (int i = 0; i < 4; i++) {
          int m = mbase + wr * 64 + mf * 16 + (l >> 4) * 4 + i;
          int n = nbase + wc * 64 + nf * 16 + (l & 15);
          float v = (acc[mf][nf][i] + bias[n]) * scale;
          int b = m >> 11, s = m & 2047;
          int h = n >> 8, d = n & 255;
          ((short*)out)[((size_t)(b * H_ + h) * S_ + s) * C_ + d] = f2bf(v);
        }
  } else if (MODE == 2) {
#pragma unroll
    for (int mf = 0; mf < 4; mf++)
#pragma unroll
      for (int nf = 0; nf < 4; nf++)
#pragma unroll
        for (int i = 0; i < 4; i++) {
          int m = mbase + wr * 64 + mf * 16 + (l >> 4) * 4 + i;
          int n = nbase + wc * 64 + nf * 16 + (l & 15);
          ((float*)out)[(size_t)m * N + n] = acc[mf][nf][i] + bias[n];
        }
  } else {
    short* T = (short*)smem;  // [128][136]
#pragma unroll
    for (int mf = 0; mf < 4; mf++)
#pragma unroll
      for (int nf = 0; nf < 4; nf++)
#pragma unroll
        for (int i = 0; i < 4; i++) {
          int ml = wr * 64 + mf * 16 + (l >> 4) * 4 + i;
          int nl = wc * 64 + nf * 16 + (l & 15);
          float v = acc[mf][nf][i] + bias[nbase + nl];
          T[ml * 136 + nl] = f2bf(v);
        }
    __syncthreads();
    int b = mbase >> 11, s0 = mbase & 2047;
    int h = nbase >> 8, d0 = nbase & 255;
#pragma unroll
    for (int r = 0; r < 8; r++) {
      int dl = r * 16 + (tid >> 4);
      int sc = (tid & 15) * 8;
      bf16x8 pack;
#pragma unroll
      for (int j = 0; j < 8; j++) pack[j] = T[(sc + j) * 136 + dl];
      *(bf16x8*)((short*)out + ((size_t)(b * H_ + h) * C_ + d0 + dl) * S_ + s0 + sc) = pack;
    }
  }
}

// ---------------- flash attention (4 waves, 32-row tiles, dbuf, counted vmcnt)
// grid 512 = 2 blocks/CU (64 KB LDS each). orig = head*16 + qtile, XCD-chunked.
// Wave owns 32 q-rows. Swapped QK^T (mfma(K,Q)) + T12 in-register softmax/pack.
// LDS per buf: Ks [32 k-rows][512B] 5-bit XOR slot swizzle;
//              Vs [32 rows][512B] = V^T 8 d-rows (64B each) per row, same XOR.
__global__ void __launch_bounds__(256, 2) attn_k(
    const short* __restrict__ Qg, const short* __restrict__ Kg,
    const short* __restrict__ Vtg, short* __restrict__ Ag) {
  __shared__ char smem[65536];
  const int tid = threadIdx.x, l = tid & 63, w = tid >> 6;   // w = 0..3
  const int hi = l >> 5;
  const int lq = l & 31;

  const int orig = (blockIdx.x & 7) * 64 + (blockIdx.x >> 3);  // bijective XCD chunk
  const int head = orig >> 4;
  const int qbase = (orig & 15) * 128 + w * 32;

  // Q fragments (B-operand): lane col q = lq, elem j <-> d = ks*16 + hi*8 + j
  bf16x8 qf[16];
  {
    const short* qb = Qg + ((size_t)head * S_ + qbase + lq) * C_;
#pragma unroll
    for (int ks = 0; ks < 16; ks++) {
      qf[ks] = *(const bf16x8*)(qb + ks * 16 + hi * 8);
      asm volatile("" : "+v"(qf[ks]));  // force materialize pre-loop (waitcnt lands here)
    }
  }

  f32x16 o[8];
#pragma unroll
  for (int dt = 0; dt < 8; dt++)
#pragma unroll
    for (int r = 0; r < 16; r++) o[dt][r] = 0.0f;
  float mrun = -__builtin_inff();
  float lrun = 0.0f;

  // staging offsets: wave w stages segs {4w+j} (j=0..3) of each 16 KB tile.
  // seg g covers rows {2g, 2g+1}; this lane handles row = 8w+2j+hi, slot lq.
  uint32_t offk[4], offv[4];
#pragma unroll
  for (int j = 0; j < 4; j++) {
    int row = 8 * w + 2 * j + hi;       // 0..31
    int cs = lq ^ row;                  // logical slot staged into LDS slot lq
    offk[j] = (uint32_t)(row * 512 + cs * 16);
    int d = 8 * row + (cs >> 2);        // V: d-row, k-chunk = cs&3
    offv[j] = (uint32_t)(d * 4096 + (cs & 3) * 16);
  }

  const char* kp = (const char*)Kg + (size_t)head * S_ * C_ * 2;
  const char* vp = (const char*)Vtg + (size_t)head * C_ * S_ * 2;

  // STAGE tile kt into buffer buf (8 gld16 per lane-wave: 4 K + 4 V)
  auto STAGE = [&](int kt, int buf) {
    char* Kd = smem + buf * 32768;
    char* Vd = Kd + 16384;
    const char* kq = kp + (uint32_t)kt * 16384;
    const char* vq = vp + (uint32_t)kt * 64;
#pragma unroll
    for (int j = 0; j < 4; j++)
      gld16(kq + offk[j], Kd + (4 * w + j) * 1024);
#pragma unroll
    for (int j = 0; j < 4; j++)
      gld16(vq + offv[j], Vd + (4 * w + j) * 1024);
  };

  STAGE(0, 0);

#pragma unroll 1
  for (int kt = 0; kt < 64; ++kt) {
    const int cur = kt & 1;
    if (kt < 63) {
      STAGE(kt + 1, cur ^ 1);
      asm volatile("s_waitcnt vmcnt(8)" ::: "memory");  // cur's 8 done, next in flight
    } else {
      asm volatile("s_waitcnt vmcnt(0)" ::: "memory");
    }
    __builtin_amdgcn_s_barrier();

    const char* Ks = smem + cur * 32768;
    const char* Vs = Ks + 16384;

    // ---- S^T tile: 32 k-rows x 32 q
    f32x16 st;
#pragma unroll
    for (int r = 0; r < 16; r++) st[r] = 0.0f;
    __builtin_amdgcn_s_setprio(1);
#pragma unroll
    for (int ks = 0; ks < 16; ks++) {
      bf16x8 kf = *(const bf16x8*)(Ks + lq * 512 + (((ks * 2 + hi) ^ lq) << 4));
      st = __builtin_amdgcn_mfma_f32_32x32x16_bf16(kf, qf[ks], st, 0, 0, 0);
    }
    __builtin_amdgcn_s_setprio(0);

    // ---- online softmax (lane owns q = lq; regs = 16 of 32 k-rows)
    float pm = st[0];
#pragma unroll
    for (int r = 1; r < 16; r++) pm = fmaxf(pm, st[r]);
    pm = fmaxf(pm, __shfl_xor(pm, 32));
    if (!__all(pm <= mrun + 8.0f)) {     // defer-max (T13)
      float mn = fmaxf(mrun, pm);
      float al = exp2f((mrun - mn) * 1.44269504f);
      mrun = mn;
      lrun *= al;
#pragma unroll
      for (int dt = 0; dt < 8; dt++) o[dt] *= al;
    }
    float mL = mrun * 1.44269504f;
    float rs = 0.f;
#pragma unroll
    for (int r = 0; r < 16; r++) {
      float p = exp2f(st[r] * 1.44269504f - mL);
      st[r] = p;
      rs += p;
    }
    rs += __shfl_xor(rs, 32);
    lrun += rs;

    // ---- pack (T12) + PV in two halves (k 0..15, then k 16..31)
    __builtin_amdgcn_s_setprio(1);
    {
      int a0 = cvtpk(st[0], st[1]), a1 = cvtpk(st[2], st[3]);
      int a2 = cvtpk(st[4], st[5]), a3 = cvtpk(st[6], st[7]);
      auto s0 = __builtin_amdgcn_permlane32_swap(a0, a2, false, false);
      auto s1 = __builtin_amdgcn_permlane32_swap(a1, a3, false, false);
      bf16x8 pf0 = pack4(s0[0], s1[0], s0[1], s1[1]);
#pragma unroll
      for (int dt = 0; dt < 8; dt++) {
        int rV = 4 * dt + (lq >> 3);
        int ls = ((lq & 7) << 2) + hi;          // k-chunk 0/1
        bf16x8 v0 = *(const bf16x8*)(Vs + rV * 512 + ((ls ^ rV) << 4));
        o[dt] = __builtin_amdgcn_mfma_f32_32x32x16_bf16(v0, pf0, o[dt], 0, 0, 0);
      }
    }
    {
      int a4 = cvtpk(st[8], st[9]),   a5 = cvtpk(st[10], st[11]);
      int a6 = cvtpk(st[12], st[13]), a7 = cvtpk(st[14], st[15]);
      auto s2 = __builtin_amdgcn_permlane32_swap(a4, a6, false, false);
      auto s3 = __builtin_amdgcn_permlane32_swap(a5, a7, false, false);
      bf16x8 pf1 = pack4(s2[0], s3[0], s2[1], s3[1]);
#pragma unroll
      for (int dt = 0; dt < 8; dt++) {
        int rV = 4 * dt + (lq >> 3);
        int ls = ((lq & 7) << 2) + 2 + hi;      // k-chunk 2/3
        bf16x8 v1 = *(const bf16x8*)(Vs + rV * 512 + ((ls ^ rV) << 4));
        o[dt] = __builtin_amdgcn_mfma_f32_32x32x16_bf16(v1, pf1, o[dt], 0, 0, 0);
      }
    }
    __builtin_amdgcn_s_setprio(0);

    asm volatile("" ::: "memory");      // pin LDS reads before barrier
    __builtin_amdgcn_s_barrier();       // cur free for restage at kt+1
  }

  // ---- epilogue: O^T (d regs x q cols) -> LDS (swizzled) -> coalesced store
  char* ob = smem + w * 16384;  // per-wave 32 q-rows x 512B
  float inv = 1.0f / lrun;
#pragma unroll
  for (int dt = 0; dt < 8; dt++) {
#pragma unroll
    for (int m = 0; m < 4; m++) {
      int lo32 = cvtpk(o[dt][4 * m + 0] * inv, o[dt][4 * m + 1] * inv);
      int hi32 = cvtpk(o[dt][4 * m + 2] * inv, o[dt][4 * m + 3] * inv);
      int cs = (dt * 4 + m) ^ lq;
      int* p = (int*)(ob + lq * 512 + cs * 16 + hi * 8);
      p[0] = lo32; p[1] = hi32;
    }
  }
  int bb = head >> 3, hh = head & 7;
#pragma unroll
  for (int pi = 0; pi < 16; pi++) {
    int qr = pi * 2 + hi;
    bf16x8 v = *(const bf16x8*)(ob + qr * 512 + ((lq ^ qr) << 4));
    size_t g = ((size_t)(bb * S_ + qbase + qr) * (H_ * C_)) + hh * C_ + lq * 8;
    *(bf16x8*)(Ag + g) = v;
  }
}

// ---------------- launch ----------------------------------------------------
extern "C" void kernel_launch(void* const* d_in, const int* in_sizes, int n_in,
                              void* d_out, int out_size, void* d_ws, size_t ws_size,
                              hipStream_t stream) {
  const float* x  = (const float*)d_in[0];
  const float* Wq = (const float*)d_in[1];
  const float* bq = (const float*)d_in[2];
  const float* Wk = (const float*)d_in[3];
  const float* bk = (const float*)d_in[4];
  const float* Wv = (const float*)d_in[5];
  const float* bv = (const float*)d_in[6];
  const float* Wo = (const float*)d_in[7];
  const float* bo = (const float*)d_in[8];

  char* ws = (char*)d_ws;
  short* xb  = (short*)(ws);               //  4 MB
  short* WqT = (short*)(ws + 4194304);     //  1 MB
  short* WkT = (short*)(ws + 5242880);
  short* WvT = (short*)(ws + 6291456);
  short* WoT = (short*)(ws + 7340032);
  short* Qg  = (short*)(ws + 8388608);     // 32 MB (B,H,S,C)
  short* Kg  = (short*)(ws + 41943040);    // 32 MB (B,H,S,C)
  short* Vt  = (short*)(ws + 75497472);    // 32 MB (B,H,C,S)
  short* Ag  = (short*)(ws + 109051904);   // 32 MB (B,S,H*C)

  cvt_f32_bf16<<<1024, 256, 0, stream>>>(x, xb, 8192 * 256);
  transpose_cvt<<<dim3(64, 8), 256, 0, stream>>>(Wq, WqT, 256, 2048);
  transpose_cvt<<<dim3(64, 8), 256, 0, stream>>>(Wk, WkT, 256, 2048);
  transpose_cvt<<<dim3(64, 8), 256, 0, stream>>>(Wv, WvT, 256, 2048);
  transpose_cvt<<<dim3(8, 64), 256, 0, stream>>>(Wo, WoT, 2048, 256);

  const float sc = 0.25f;  // 256^(-1/4)
  gemm_k<0><<<dim3(16, 64), 256, 0, stream>>>(xb, WqT, bq, sc, Qg, 8192, 2048, 256);
  gemm_k<0><<<dim3(16, 64), 256, 0, stream>>>(xb, WkT, bk, sc, Kg, 8192, 2048, 256);
  gemm_k<1><<<dim3(16, 64), 256, 0, stream>>>(xb, WvT, bv, 1.0f, Vt, 8192, 2048, 256);
  attn_k<<<512, 256, 0, stream>>>(Qg, Kg, Vt, Ag);
  gemm_k<2><<<dim3(2, 64), 256, 0, stream>>>(Ag, WoT, bo, 1.0f, (float*)d_out, 8192, 256, 2048);
}